// Round 1
// baseline (7463.001 us; speedup 1.0000x reference)
//
#include <hip/hip_runtime.h>
#include <hip/hip_bf16.h>
#include <math.h>

// Problem constants
#define S   2048
#define E   256
#define HD  256
#define NCOL 2048   // 2 dirs * 4 gates * HD
#define NT  48
#define NWG 16      // recurrence workgroups

// ---------------- workspace layout (bytes) ----------------
#define XZ_OFF      ((size_t)0)                         // float[S][2048]
#define XZ_BYTES    ((size_t)S * 2048 * 4)
#define LSTM_OFF    (XZ_OFF + XZ_BYTES)                 // float[S][512]
#define LSTM_BYTES  ((size_t)S * 512 * 4)
#define FEATS_OFF   (LSTM_OFF + LSTM_BYTES)             // float[S][48]
#define FEATS_BYTES ((size_t)S * NT * 4)
#define HCUR_OFF    (FEATS_OFF + FEATS_BYTES)           // float[2 phase][2 dir][256]
#define HCUR_BYTES  ((size_t)2 * 2 * 256 * 4)
#define BAR_OFF     (HCUR_OFF + HCUR_BYTES)             // unsigned[16]
#define BAR_BYTES   ((size_t)64)
#define BPS_OFF     (BAR_OFF + BAR_BYTES)               // u8[2048][48]
#define BPS_BYTES   ((size_t)S * NT)
#define PATHA_OFF   (BPS_OFF + BPS_BYTES)               // u8[3072][32]
#define PATHA_BYTES ((size_t)3072 * 32)

// =========================================================
// Kernel 1: xz[t][col] = emb[sent[t]] @ [Wih_f;Wih_b].T + [b_f;b_b]
// 128x128 tile, K=256 in chunks of 16, 256 threads, 8x8 per thread
// =========================================================
__global__ __launch_bounds__(256) void gemm_xz(
    const int* __restrict__ sent, const float* __restrict__ emb,
    const float* __restrict__ Wih_f, const float* __restrict__ Wih_b,
    const float* __restrict__ b_f, const float* __restrict__ b_b,
    float* __restrict__ xz)
{
    __shared__ float As[16][132];
    __shared__ float Bs[16][132];
    const int tid = threadIdx.x;
    const int bm = blockIdx.x * 128;   // t tile
    const int bn = blockIdx.y * 128;   // col tile
    const int tx = tid & 15, ty = tid >> 4;
    const int lm = tid >> 1, kq = (tid & 1) * 8;

    const int srow = sent[bm + lm];
    const float* arow = emb + (size_t)srow * E;
    const int bcol = bn + lm;
    const float* brow = (bcol < 1024) ? (Wih_f + (size_t)bcol * E)
                                      : (Wih_b + (size_t)(bcol - 1024) * E);
    float acc[8][8];
#pragma unroll
    for (int i = 0; i < 8; ++i)
#pragma unroll
        for (int j = 0; j < 8; ++j) acc[i][j] = 0.f;

    for (int k0 = 0; k0 < 256; k0 += 16) {
        float4 a0 = *(const float4*)(arow + k0 + kq);
        float4 a1 = *(const float4*)(arow + k0 + kq + 4);
        float4 c0v = *(const float4*)(brow + k0 + kq);
        float4 c1v = *(const float4*)(brow + k0 + kq + 4);
        __syncthreads();
        As[kq + 0][lm] = a0.x; As[kq + 1][lm] = a0.y; As[kq + 2][lm] = a0.z; As[kq + 3][lm] = a0.w;
        As[kq + 4][lm] = a1.x; As[kq + 5][lm] = a1.y; As[kq + 6][lm] = a1.z; As[kq + 7][lm] = a1.w;
        Bs[kq + 0][lm] = c0v.x; Bs[kq + 1][lm] = c0v.y; Bs[kq + 2][lm] = c0v.z; Bs[kq + 3][lm] = c0v.w;
        Bs[kq + 4][lm] = c1v.x; Bs[kq + 5][lm] = c1v.y; Bs[kq + 6][lm] = c1v.z; Bs[kq + 7][lm] = c1v.w;
        __syncthreads();
#pragma unroll
        for (int k = 0; k < 16; ++k) {
            float av[8], bv[8];
            *(float4*)&av[0] = *(const float4*)&As[k][ty * 8];
            *(float4*)&av[4] = *(const float4*)&As[k][ty * 8 + 4];
            *(float4*)&bv[0] = *(const float4*)&Bs[k][tx * 8];
            *(float4*)&bv[4] = *(const float4*)&Bs[k][tx * 8 + 4];
#pragma unroll
            for (int i = 0; i < 8; ++i)
#pragma unroll
                for (int j = 0; j < 8; ++j) acc[i][j] += av[i] * bv[j];
        }
    }
    // epilogue: add bias, store
    float bias[8];
    const int cb = bn + tx * 8;
    const float* bptr = (cb < 1024) ? (b_f + cb) : (b_b + cb - 1024);
    *(float4*)&bias[0] = *(const float4*)bptr;
    *(float4*)&bias[4] = *(const float4*)(bptr + 4);
#pragma unroll
    for (int i = 0; i < 8; ++i) {
        const int trow = bm + ty * 8 + i;
        float4 o0, o1;
        o0.x = acc[i][0] + bias[0]; o0.y = acc[i][1] + bias[1];
        o0.z = acc[i][2] + bias[2]; o0.w = acc[i][3] + bias[3];
        o1.x = acc[i][4] + bias[4]; o1.y = acc[i][5] + bias[5];
        o1.z = acc[i][6] + bias[6]; o1.w = acc[i][7] + bias[7];
        *(float4*)(xz + (size_t)trow * NCOL + cb) = o0;
        *(float4*)(xz + (size_t)trow * NCOL + cb + 4) = o1;
    }
}

// =========================================================
// Kernel 2: persistent bidirectional LSTM recurrence.
// 16 wgs x 256 threads. wg owns hidden units [wg*16, wg*16+16) for BOTH
// directions (4 gates each = 128 rows). Weights in VGPRs (128 fp32/thread).
// Thread (kg,rg): kg=tid>>4 (k-slice of 16), rg=tid&15 (8 rows each).
// Per step: matvec -> shfl/LDS reduce -> gates -> write h -> global barrier.
// =========================================================
__global__ void __launch_bounds__(256, 1) lstm_rec(
    const float* __restrict__ Whh_f, const float* __restrict__ Whh_b,
    const float* __restrict__ h0, const float* __restrict__ c0,
    const float* __restrict__ xz, float* __restrict__ hcur,
    float* __restrict__ lstm_out, unsigned int* __restrict__ bar)
{
    __shared__ float red[4][16][8];
    __shared__ float zbuf[128];
    const int wg = blockIdx.x;
    const int tid = threadIdx.x;
    const int kg = tid >> 4;        // 0..15
    const int rg = tid & 15;        // 0..15
    const int dir = rg >> 3;        // 0 fwd, 1 bwd
    const int rgd = rg & 7;
    const int k0 = kg * 16;
    const float* Whh = dir ? Whh_b : Whh_f;

    // load weights into registers: 8 rows x 16 k
    float w[8][16];
#pragma unroll
    for (int q = 0; q < 8; ++q) {
        const int lrd = rgd * 8 + q;                    // 0..63 within dir
        const int grow = (lrd >> 4) * 256 + wg * 16 + (lrd & 15);
        const float* wr = Whh + (size_t)grow * 256 + k0;
#pragma unroll
        for (int kk = 0; kk < 16; kk += 4) {
            float4 v = *(const float4*)(wr + kk);
            w[q][kk] = v.x; w[q][kk + 1] = v.y; w[q][kk + 2] = v.z; w[q][kk + 3] = v.w;
        }
    }
    // persistent cell state for gate threads
    float cst = 0.f;
    if (tid < 32) cst = c0[(tid >> 4) * 256 + wg * 16 + (tid & 15)];
    // z-row mapping for tid<128
    const int zdir = tid >> 6, zlr = tid & 63;
    const int zcol = zdir * 1024 + (zlr >> 4) * 256 + wg * 16 + (zlr & 15);

    unsigned phase = 0;
    for (int step = 0; step < S; ++step) {
        // prefetch precomputed input part
        float xzv = 0.f;
        if (tid < 128) {
            const int tz = zdir ? (S - 1 - step) : step;
            xzv = xz[(size_t)tz * NCOL + zcol];
        }
        const float* hsrc = (step == 0) ? (h0 + dir * 256 + k0)
                                        : (hcur + ((size_t)phase * 2 + dir) * 256 + k0);
        float h16[16];
#pragma unroll
        for (int kk = 0; kk < 16; kk += 4) {
            float4 v = *(const float4*)(hsrc + kk);
            h16[kk] = v.x; h16[kk + 1] = v.y; h16[kk + 2] = v.z; h16[kk + 3] = v.w;
        }
        float acc[8];
#pragma unroll
        for (int q = 0; q < 8; ++q) acc[q] = 0.f;
#pragma unroll
        for (int kk = 0; kk < 16; ++kk)
#pragma unroll
            for (int q = 0; q < 8; ++q) acc[q] += w[q][kk] * h16[kk];
        // butterfly over the 4 k-groups within this wave
#pragma unroll
        for (int q = 0; q < 8; ++q) {
            acc[q] += __shfl_xor(acc[q], 16);
            acc[q] += __shfl_xor(acc[q], 32);
        }
        if ((kg & 3) == 0) {
            const int wv = kg >> 2;
#pragma unroll
            for (int q = 0; q < 8; ++q) red[wv][rg][q] = acc[q];
        }
        __syncthreads();
        if (tid < 128) {
            const int rg2 = tid >> 3, q2 = tid & 7;
            float z = ((red[0][rg2][q2] + red[1][rg2][q2]) +
                       (red[2][rg2][q2] + red[3][rg2][q2])) + xzv;
            zbuf[tid] = z;
        }
        __syncthreads();
        if (tid < 32) {
            const int dz = tid >> 4, hu = tid & 15;
            const float zi = zbuf[dz * 64 + hu];
            const float zf = zbuf[dz * 64 + 16 + hu];
            const float zg = zbuf[dz * 64 + 32 + hu];
            const float zo = zbuf[dz * 64 + 48 + hu];
            const float ig = 1.f / (1.f + expf(-zi));
            const float fg = 1.f / (1.f + expf(-zf));
            const float gg = tanhf(zg);
            const float og = 1.f / (1.f + expf(-zo));
            cst = fg * cst + ig * gg;
            const float h = og * tanhf(cst);
            const int tz = dz ? (S - 1 - step) : step;
            const int hidx = wg * 16 + hu;
            lstm_out[(size_t)tz * 512 + dz * 256 + hidx] = h;
            hcur[(((size_t)(phase ^ 1)) * 2 + dz) * 256 + hidx] = h;
            __threadfence();
        }
        __syncthreads();
        if (step < S - 1) {
            if (tid == 0) {
                __threadfence();
                atomicAdd(bar, 1u);
                const unsigned target = (unsigned)(step + 1) * NWG;
                while (__hip_atomic_load(bar, __ATOMIC_ACQUIRE, __HIP_MEMORY_SCOPE_AGENT) < target) {
                    __builtin_amdgcn_s_sleep(2);
                }
            }
            __syncthreads();
        }
        phase ^= 1;
    }
}

// =========================================================
// Kernel 3: feats[t][tag] = lstm_out[t] . W_out[tag] + b_out[tag]
// =========================================================
__global__ __launch_bounds__(256) void feats_k(
    const float* __restrict__ lstm, const float* __restrict__ Wout,
    const float* __restrict__ bout, float* __restrict__ feats)
{
    const int gid = blockIdx.x * 256 + threadIdx.x;
    if (gid >= S * NT) return;
    const int t = gid / NT, tag = gid - t * NT;
    const float* hr = lstm + (size_t)t * 512;
    const float* wr = Wout + (size_t)tag * 512;
    float s0 = 0, s1 = 0, s2 = 0, s3 = 0;
#pragma unroll 4
    for (int k = 0; k < 512; k += 4) {
        float4 h4 = *(const float4*)(hr + k);
        float4 w4 = *(const float4*)(wr + k);
        s0 += h4.x * w4.x; s1 += h4.y * w4.y;
        s2 += h4.z * w4.z; s3 += h4.w * w4.w;
    }
    feats[gid] = (s0 + s1) + (s2 + s3) + bout[tag];
}

// =========================================================
// Kernel 4: Viterbi forward (exact reference order + first-index tie-break)
// then chunked parallel backtrack. One workgroup, 256 threads.
// =========================================================
__global__ void __launch_bounds__(256, 1) viterbi_k(
    const float* __restrict__ feats, const float* __restrict__ trans,
    unsigned char* __restrict__ bps, unsigned char* __restrict__ pathA,
    int* __restrict__ out)
{
    __shared__ float v2[2][NT];
    __shared__ unsigned char cmap[64][NT];
    __shared__ int SB[65];
    __shared__ int last_s;
    const int tid = threadIdx.x;
    const int j = tid >> 2, ig = tid & 3;
    const bool act = (tid < 192);

    float Treg[12];
    if (act) {
#pragma unroll
        for (int r = 0; r < 12; ++r) Treg[r] = trans[(ig * 12 + r) * NT + j];
    }
    if (tid < NT) v2[0][tid] = feats[tid];
    __syncthreads();

    float obs_c = 0.f;
    if (act) obs_c = feats[NT + j];
    for (int t = 1; t < S; ++t) {
        float obs_n = 0.f;
        if (act && t < S - 1) obs_n = feats[(size_t)(t + 1) * NT + j];
        const int p = (t - 1) & 1;
        if (act) {
            float best = -1e30f; int bi = 0;
#pragma unroll
            for (int r = 0; r < 12; ++r) {
                const int i = ig * 12 + r;
                const float sc = (v2[p][i] + Treg[r]) + obs_c;
                if (sc > best) { best = sc; bi = i; }
            }
            // reduce across the 4 i-groups; first-index wins ties
            {
                float ob = __shfl_xor(best, 1); int obi = __shfl_xor(bi, 1);
                if (ob > best || (ob == best && obi < bi)) { best = ob; bi = obi; }
                ob = __shfl_xor(best, 2); obi = __shfl_xor(bi, 2);
                if (ob > best || (ob == best && obi < bi)) { best = ob; bi = obi; }
            }
            if (ig == 0) {
                v2[p ^ 1][j] = best;
                bps[(size_t)(t - 1) * NT + j] = (unsigned char)bi;
            }
        }
        __syncthreads();
        obs_c = obs_n;
    }
    // last = argmax of final v (stored in v2[1]); first occurrence
    if (tid == 0) {
        float b = -1e30f; int bi = 0;
        for (int q = 0; q < NT; ++q) { if (v2[1][q] > b) { b = v2[1][q]; bi = q; } }
        last_s = bi;
    }
    // Phase A: 64 chunks x 48 states, 12 tasks/thread, ILP-12 chains
    int cArr[12], sArr[12];
    unsigned char stv[12];
#pragma unroll
    for (int r = 0; r < 12; ++r) {
        const int task = r * 256 + tid;
        cArr[r] = task / NT;
        sArr[r] = task - cArr[r] * NT;
        stv[r] = (unsigned char)sArr[r];
    }
    for (int stp = 31; stp >= 0; --stp) {
#pragma unroll
        for (int r = 0; r < 12; ++r) {
            const int km = cArr[r] * 32 + stp;
            if (km < S - 1) stv[r] = bps[(size_t)km * NT + stv[r]];
            pathA[(size_t)(cArr[r] * NT + sArr[r]) * 32 + stp] = stv[r];
        }
    }
#pragma unroll
    for (int r = 0; r < 12; ++r) cmap[cArr[r]][sArr[r]] = stv[r];
    __syncthreads();
    // Phase B: sequential chunk-boundary states
    if (tid == 0) {
        SB[64] = last_s;
        for (int c = 63; c >= 0; --c) SB[c] = cmap[c][SB[c + 1]];
    }
    __syncthreads();
    // Phase C: emit path
    for (int t = tid; t < S; t += 256) {
        const int c = t >> 5;
        out[t] = (int)pathA[(size_t)(c * NT + SB[c + 1]) * 32 + (t & 31)];
    }
}

// =========================================================
extern "C" void kernel_launch(void* const* d_in, const int* in_sizes, int n_in,
                              void* d_out, int out_size, void* d_ws, size_t ws_size,
                              hipStream_t stream) {
    const int*   sent   = (const int*)d_in[0];
    const float* emb    = (const float*)d_in[1];
    const float* Wih_f  = (const float*)d_in[2];
    const float* Whh_f  = (const float*)d_in[3];
    const float* b_f    = (const float*)d_in[4];
    const float* Wih_b  = (const float*)d_in[5];
    const float* Whh_b  = (const float*)d_in[6];
    const float* b_b    = (const float*)d_in[7];
    const float* W_out  = (const float*)d_in[8];
    const float* b_out  = (const float*)d_in[9];
    const float* trans  = (const float*)d_in[10];
    const float* h0     = (const float*)d_in[11];
    const float* c0     = (const float*)d_in[12];
    int* out = (int*)d_out;

    char* ws = (char*)d_ws;
    float* xz       = (float*)(ws + XZ_OFF);
    float* lstm     = (float*)(ws + LSTM_OFF);
    float* feats    = (float*)(ws + FEATS_OFF);
    float* hcur     = (float*)(ws + HCUR_OFF);
    unsigned* bar   = (unsigned*)(ws + BAR_OFF);
    unsigned char* bps   = (unsigned char*)(ws + BPS_OFF);
    unsigned char* pathA = (unsigned char*)(ws + PATHA_OFF);

    hipMemsetAsync(bar, 0, BAR_BYTES, stream);

    gemm_xz<<<dim3(16, 16), 256, 0, stream>>>(sent, emb, Wih_f, Wih_b, b_f, b_b, xz);

    void* args[] = { (void*)&Whh_f, (void*)&Whh_b, (void*)&h0, (void*)&c0,
                     (void*)&xz, (void*)&hcur, (void*)&lstm, (void*)&bar };
    hipLaunchCooperativeKernel((void*)lstm_rec, dim3(NWG), dim3(256), args, 0, stream);

    feats_k<<<dim3((S * NT + 255) / 256), 256, 0, stream>>>(lstm, W_out, b_out, feats);

    viterbi_k<<<dim3(1), 256, 0, stream>>>(feats, trans, bps, pathA, out);
}

// Round 2
// 7427.941 us; speedup vs baseline: 1.0047x; 1.0047x over previous
//
#include <hip/hip_runtime.h>
#include <hip/hip_bf16.h>
#include <math.h>

// Problem constants
#define S   2048
#define E   256
#define HD  256
#define NCOL 2048   // 2 dirs * 4 gates * HD
#define NT  48
#define NWG 16      // recurrence workgroups (8 per direction)

// ---------------- workspace layout (bytes) ----------------
#define XZ_OFF      ((size_t)0)                         // float[S][2048]
#define XZ_BYTES    ((size_t)S * 2048 * 4)
#define LSTM_OFF    (XZ_OFF + XZ_BYTES)                 // float[S][512]
#define LSTM_BYTES  ((size_t)S * 512 * 4)
#define FEATS_OFF   (LSTM_OFF + LSTM_BYTES)             // float[S][48]
#define FEATS_BYTES ((size_t)S * NT * 4)
#define HCUR_OFF    (FEATS_OFF + FEATS_BYTES)           // float[2 phase][2 dir][256]
#define HCUR_BYTES  ((size_t)2 * 2 * 256 * 4)
#define FLAG_OFF    (HCUR_OFF + HCUR_BYTES)             // unsigned[16][16] (64B-strided flags)
#define FLAG_BYTES  ((size_t)16 * 16 * 4)
#define BPS_OFF     (FLAG_OFF + FLAG_BYTES)             // u8[2048][48]
#define BPS_BYTES   ((size_t)S * NT)
#define PATHA_OFF   (BPS_OFF + BPS_BYTES)               // u8[3072][32]
#define PATHA_BYTES ((size_t)3072 * 32)

// =========================================================
// Kernel 1: xz[t][col] = emb[sent[t]] @ [Wih_f;Wih_b].T + [b_f;b_b]
// 128x128 tile, K=256 in chunks of 16, 256 threads, 8x8 per thread
// =========================================================
__global__ __launch_bounds__(256) void gemm_xz(
    const int* __restrict__ sent, const float* __restrict__ emb,
    const float* __restrict__ Wih_f, const float* __restrict__ Wih_b,
    const float* __restrict__ b_f, const float* __restrict__ b_b,
    float* __restrict__ xz)
{
    __shared__ float As[16][132];
    __shared__ float Bs[16][132];
    const int tid = threadIdx.x;
    const int bm = blockIdx.x * 128;   // t tile
    const int bn = blockIdx.y * 128;   // col tile
    const int tx = tid & 15, ty = tid >> 4;
    const int lm = tid >> 1, kq = (tid & 1) * 8;

    const int srow = sent[bm + lm];
    const float* arow = emb + (size_t)srow * E;
    const int bcol = bn + lm;
    const float* brow = (bcol < 1024) ? (Wih_f + (size_t)bcol * E)
                                      : (Wih_b + (size_t)(bcol - 1024) * E);
    float acc[8][8];
#pragma unroll
    for (int i = 0; i < 8; ++i)
#pragma unroll
        for (int j = 0; j < 8; ++j) acc[i][j] = 0.f;

    for (int k0 = 0; k0 < 256; k0 += 16) {
        float4 a0 = *(const float4*)(arow + k0 + kq);
        float4 a1 = *(const float4*)(arow + k0 + kq + 4);
        float4 c0v = *(const float4*)(brow + k0 + kq);
        float4 c1v = *(const float4*)(brow + k0 + kq + 4);
        __syncthreads();
        As[kq + 0][lm] = a0.x; As[kq + 1][lm] = a0.y; As[kq + 2][lm] = a0.z; As[kq + 3][lm] = a0.w;
        As[kq + 4][lm] = a1.x; As[kq + 5][lm] = a1.y; As[kq + 6][lm] = a1.z; As[kq + 7][lm] = a1.w;
        Bs[kq + 0][lm] = c0v.x; Bs[kq + 1][lm] = c0v.y; Bs[kq + 2][lm] = c0v.z; Bs[kq + 3][lm] = c0v.w;
        Bs[kq + 4][lm] = c1v.x; Bs[kq + 5][lm] = c1v.y; Bs[kq + 6][lm] = c1v.z; Bs[kq + 7][lm] = c1v.w;
        __syncthreads();
#pragma unroll
        for (int k = 0; k < 16; ++k) {
            float av[8], bv[8];
            *(float4*)&av[0] = *(const float4*)&As[k][ty * 8];
            *(float4*)&av[4] = *(const float4*)&As[k][ty * 8 + 4];
            *(float4*)&bv[0] = *(const float4*)&Bs[k][tx * 8];
            *(float4*)&bv[4] = *(const float4*)&Bs[k][tx * 8 + 4];
#pragma unroll
            for (int i = 0; i < 8; ++i)
#pragma unroll
                for (int j = 0; j < 8; ++j) acc[i][j] += av[i] * bv[j];
        }
    }
    // epilogue: add bias, store
    float bias[8];
    const int cb = bn + tx * 8;
    const float* bptr = (cb < 1024) ? (b_f + cb) : (b_b + cb - 1024);
    *(float4*)&bias[0] = *(const float4*)bptr;
    *(float4*)&bias[4] = *(const float4*)(bptr + 4);
#pragma unroll
    for (int i = 0; i < 8; ++i) {
        const int trow = bm + ty * 8 + i;
        float4 o0, o1;
        o0.x = acc[i][0] + bias[0]; o0.y = acc[i][1] + bias[1];
        o0.z = acc[i][2] + bias[2]; o0.w = acc[i][3] + bias[3];
        o1.x = acc[i][4] + bias[4]; o1.y = acc[i][5] + bias[5];
        o1.z = acc[i][6] + bias[6]; o1.w = acc[i][7] + bias[7];
        *(float4*)(xz + (size_t)trow * NCOL + cb) = o0;
        *(float4*)(xz + (size_t)trow * NCOL + cb + 4) = o1;
    }
}

// =========================================================
// Kernel 2: persistent bidirectional LSTM recurrence, v2.
// 16 wgs x 256 threads. WGs 0-7 = forward dir, 8-15 = backward dir.
// Each WG owns 32 hidden units of ONE direction (4 gates = 128 rows),
// weights in VGPRs (128 fp32/thread).
// Sync: per-WG 64B-strided flag lines, release store by producer,
// acquire poll by consumers (each thread polls ONLY the producer that
// covers its k-slice). No central atomic, no threadfence, no s_sleep.
// Compute structure (reduction tree, gate math) identical to v1 ->
// bit-identical h output.
// =========================================================
__global__ void __launch_bounds__(256, 1) lstm_rec(
    const float* __restrict__ Whh_f, const float* __restrict__ Whh_b,
    const float* __restrict__ h0, const float* __restrict__ c0,
    const float* __restrict__ xz, float* __restrict__ hcur,
    float* __restrict__ lstm_out, unsigned int* __restrict__ flags)
{
    __shared__ float red[4][16][8];
    __shared__ float actb[128];
    const int wg = blockIdx.x;
    const int dir = wg >> 3;        // 0 fwd, 1 bwd
    const int wi = wg & 7;          // index within direction
    const int ub = wi * 32;         // first hidden unit owned
    const int tid = threadIdx.x;
    const int kg = tid >> 4;        // 0..15  k-slice (16 wide)
    const int rg = tid & 15;        // 0..15  row group (8 rows each)
    const int k0 = kg * 16;
    const float* Whh = dir ? Whh_b : Whh_f;

    // load weights into registers: 8 rows x 16 k
    float w[8][16];
#pragma unroll
    for (int q = 0; q < 8; ++q) {
        const int lr = rg * 8 + q;                      // 0..127
        const int grow = (lr >> 5) * 256 + ub + (lr & 31);
        const float* wr = Whh + (size_t)grow * 256 + k0;
#pragma unroll
        for (int kk = 0; kk < 16; kk += 4) {
            float4 v = *(const float4*)(wr + kk);
            w[q][kk] = v.x; w[q][kk + 1] = v.y; w[q][kk + 2] = v.z; w[q][kk + 3] = v.w;
        }
    }
    // persistent cell state for gate threads (tid<32 = unit tid)
    float cst = (tid < 32) ? c0[dir * 256 + ub + tid] : 0.f;
    // z-row mapping for tid<128: row = tid -> gate=tid>>5, unit=tid&31
    const int zcol = dir * 1024 + (tid >> 5) * 256 + ub + (tid & 31);
    // which producer's flag gates this thread's h16 slice [k0, k0+16)
    unsigned int* myflag = flags + ((size_t)dir * 8 + (kg >> 1)) * 16;

    for (int step = 0; step < S; ++step) {
        // prefetch precomputed input part (independent of h -> overlaps poll)
        float xzv = 0.f;
        if (tid < 128) {
            const int tz = dir ? (S - 1 - step) : step;
            xzv = xz[(size_t)tz * NCOL + zcol];
        }
        // wait for h(step-1) slice
        if (step > 0) {
            while (__hip_atomic_load(myflag, __ATOMIC_ACQUIRE,
                                     __HIP_MEMORY_SCOPE_AGENT) < (unsigned)step) {}
        }
        const float* hsrc = (step == 0) ? (h0 + dir * 256 + k0)
                                        : (hcur + ((size_t)(step & 1) * 2 + dir) * 256 + k0);
        float h16[16];
#pragma unroll
        for (int kk = 0; kk < 16; kk += 4) {
            float4 v = *(const float4*)(hsrc + kk);
            h16[kk] = v.x; h16[kk + 1] = v.y; h16[kk + 2] = v.z; h16[kk + 3] = v.w;
        }
        float acc[8];
#pragma unroll
        for (int q = 0; q < 8; ++q) acc[q] = 0.f;
#pragma unroll
        for (int kk = 0; kk < 16; ++kk)
#pragma unroll
            for (int q = 0; q < 8; ++q) acc[q] += w[q][kk] * h16[kk];
        // butterfly over the 4 k-groups within this wave
#pragma unroll
        for (int q = 0; q < 8; ++q) {
            acc[q] += __shfl_xor(acc[q], 16);
            acc[q] += __shfl_xor(acc[q], 32);
        }
        if ((kg & 3) == 0) {
            const int wv = kg >> 2;
#pragma unroll
            for (int q = 0; q < 8; ++q) red[wv][rg][q] = acc[q];
        }
        __syncthreads();
        if (tid < 128) {
            // row = tid
            const int rg2 = tid >> 3, q2 = tid & 7;
            const float z = ((red[0][rg2][q2] + red[1][rg2][q2]) +
                             (red[2][rg2][q2] + red[3][rg2][q2])) + xzv;
            const int gate = tid >> 5;
            actb[tid] = (gate == 2) ? tanhf(z) : (1.f / (1.f + expf(-z)));
        }
        __syncthreads();
        if (tid < 32) {
            const int u = tid;
            const float ig = actb[u];
            const float fg = actb[32 + u];
            const float gg = actb[64 + u];
            const float og = actb[96 + u];
            cst = fg * cst + ig * gg;
            const float h = og * tanhf(cst);
            const int tz = dir ? (S - 1 - step) : step;
            // write-through stores (no dirty L2, cheap release later)
            __hip_atomic_store(&hcur[(((size_t)((step + 1) & 1)) * 2 + dir) * 256 + ub + u],
                               h, __ATOMIC_RELAXED, __HIP_MEMORY_SCOPE_AGENT);
            __hip_atomic_store(&lstm_out[(size_t)tz * 512 + dir * 256 + ub + u],
                               h, __ATOMIC_RELAXED, __HIP_MEMORY_SCOPE_AGENT);
        }
        // publish: same wave as the h stores -> release's vmcnt(0) orders them
        if (tid == 0) {
            __hip_atomic_store(&flags[(size_t)wg * 16], (unsigned)(step + 1),
                               __ATOMIC_RELEASE, __HIP_MEMORY_SCOPE_AGENT);
        }
    }
}

// =========================================================
// Kernel 3: feats[t][tag] = lstm_out[t] . W_out[tag] + b_out[tag]
// =========================================================
__global__ __launch_bounds__(256) void feats_k(
    const float* __restrict__ lstm, const float* __restrict__ Wout,
    const float* __restrict__ bout, float* __restrict__ feats)
{
    const int gid = blockIdx.x * 256 + threadIdx.x;
    if (gid >= S * NT) return;
    const int t = gid / NT, tag = gid - t * NT;
    const float* hr = lstm + (size_t)t * 512;
    const float* wr = Wout + (size_t)tag * 512;
    float s0 = 0, s1 = 0, s2 = 0, s3 = 0;
#pragma unroll 4
    for (int k = 0; k < 512; k += 4) {
        float4 h4 = *(const float4*)(hr + k);
        float4 w4 = *(const float4*)(wr + k);
        s0 += h4.x * w4.x; s1 += h4.y * w4.y;
        s2 += h4.z * w4.z; s3 += h4.w * w4.w;
    }
    feats[gid] = (s0 + s1) + (s2 + s3) + bout[tag];
}

// =========================================================
// Kernel 4: Viterbi forward (exact reference order + first-index tie-break)
// then chunked parallel backtrack. One workgroup, 256 threads.
// =========================================================
__global__ void __launch_bounds__(256, 1) viterbi_k(
    const float* __restrict__ feats, const float* __restrict__ trans,
    unsigned char* __restrict__ bps, unsigned char* __restrict__ pathA,
    int* __restrict__ out)
{
    __shared__ float v2[2][NT];
    __shared__ unsigned char cmap[64][NT];
    __shared__ int SB[65];
    __shared__ int last_s;
    const int tid = threadIdx.x;
    const int j = tid >> 2, ig = tid & 3;
    const bool act = (tid < 192);

    float Treg[12];
    if (act) {
#pragma unroll
        for (int r = 0; r < 12; ++r) Treg[r] = trans[(ig * 12 + r) * NT + j];
    }
    if (tid < NT) v2[0][tid] = feats[tid];
    __syncthreads();

    float obs_c = 0.f;
    if (act) obs_c = feats[NT + j];
    for (int t = 1; t < S; ++t) {
        float obs_n = 0.f;
        if (act && t < S - 1) obs_n = feats[(size_t)(t + 1) * NT + j];
        const int p = (t - 1) & 1;
        if (act) {
            float best = -1e30f; int bi = 0;
#pragma unroll
            for (int r = 0; r < 12; ++r) {
                const int i = ig * 12 + r;
                const float sc = (v2[p][i] + Treg[r]) + obs_c;
                if (sc > best) { best = sc; bi = i; }
            }
            // reduce across the 4 i-groups; first-index wins ties
            {
                float ob = __shfl_xor(best, 1); int obi = __shfl_xor(bi, 1);
                if (ob > best || (ob == best && obi < bi)) { best = ob; bi = obi; }
                ob = __shfl_xor(best, 2); obi = __shfl_xor(bi, 2);
                if (ob > best || (ob == best && obi < bi)) { best = ob; bi = obi; }
            }
            if (ig == 0) {
                v2[p ^ 1][j] = best;
                bps[(size_t)(t - 1) * NT + j] = (unsigned char)bi;
            }
        }
        __syncthreads();
        obs_c = obs_n;
    }
    // last = argmax of final v (stored in v2[1]); first occurrence
    if (tid == 0) {
        float b = -1e30f; int bi = 0;
        for (int q = 0; q < NT; ++q) { if (v2[1][q] > b) { b = v2[1][q]; bi = q; } }
        last_s = bi;
    }
    // Phase A: 64 chunks x 48 states, 12 tasks/thread, ILP-12 chains
    int cArr[12], sArr[12];
    unsigned char stv[12];
#pragma unroll
    for (int r = 0; r < 12; ++r) {
        const int task = r * 256 + tid;
        cArr[r] = task / NT;
        sArr[r] = task - cArr[r] * NT;
        stv[r] = (unsigned char)sArr[r];
    }
    for (int stp = 31; stp >= 0; --stp) {
#pragma unroll
        for (int r = 0; r < 12; ++r) {
            const int km = cArr[r] * 32 + stp;
            if (km < S - 1) stv[r] = bps[(size_t)km * NT + stv[r]];
            pathA[(size_t)(cArr[r] * NT + sArr[r]) * 32 + stp] = stv[r];
        }
    }
#pragma unroll
    for (int r = 0; r < 12; ++r) cmap[cArr[r]][sArr[r]] = stv[r];
    __syncthreads();
    // Phase B: sequential chunk-boundary states
    if (tid == 0) {
        SB[64] = last_s;
        for (int c = 63; c >= 0; --c) SB[c] = cmap[c][SB[c + 1]];
    }
    __syncthreads();
    // Phase C: emit path
    for (int t = tid; t < S; t += 256) {
        const int c = t >> 5;
        out[t] = (int)pathA[(size_t)(c * NT + SB[c + 1]) * 32 + (t & 31)];
    }
}

// =========================================================
extern "C" void kernel_launch(void* const* d_in, const int* in_sizes, int n_in,
                              void* d_out, int out_size, void* d_ws, size_t ws_size,
                              hipStream_t stream) {
    const int*   sent   = (const int*)d_in[0];
    const float* emb    = (const float*)d_in[1];
    const float* Wih_f  = (const float*)d_in[2];
    const float* Whh_f  = (const float*)d_in[3];
    const float* b_f    = (const float*)d_in[4];
    const float* Wih_b  = (const float*)d_in[5];
    const float* Whh_b  = (const float*)d_in[6];
    const float* b_b    = (const float*)d_in[7];
    const float* W_out  = (const float*)d_in[8];
    const float* b_out  = (const float*)d_in[9];
    const float* trans  = (const float*)d_in[10];
    const float* h0     = (const float*)d_in[11];
    const float* c0     = (const float*)d_in[12];
    int* out = (int*)d_out;

    char* ws = (char*)d_ws;
    float* xz       = (float*)(ws + XZ_OFF);
    float* lstm     = (float*)(ws + LSTM_OFF);
    float* feats    = (float*)(ws + FEATS_OFF);
    float* hcur     = (float*)(ws + HCUR_OFF);
    unsigned* flags = (unsigned*)(ws + FLAG_OFF);
    unsigned char* bps   = (unsigned char*)(ws + BPS_OFF);
    unsigned char* pathA = (unsigned char*)(ws + PATHA_OFF);

    hipMemsetAsync(flags, 0, FLAG_BYTES, stream);

    gemm_xz<<<dim3(16, 16), 256, 0, stream>>>(sent, emb, Wih_f, Wih_b, b_f, b_b, xz);

    void* args[] = { (void*)&Whh_f, (void*)&Whh_b, (void*)&h0, (void*)&c0,
                     (void*)&xz, (void*)&hcur, (void*)&lstm, (void*)&flags };
    hipLaunchCooperativeKernel((void*)lstm_rec, dim3(NWG), dim3(256), args, 0, stream);

    feats_k<<<dim3((S * NT + 255) / 256), 256, 0, stream>>>(lstm, W_out, b_out, feats);

    viterbi_k<<<dim3(1), 256, 0, stream>>>(feats, trans, bps, pathA, out);
}